// Round 15
// baseline (309.723 us; speedup 1.0000x reference)
//
#include <hip/hip_runtime.h>
#include <cstddef>
#include <cmath>

#define NB  4096
#define TT  200
#define DD  64
#define NH1 80
#define NH2 40

typedef _Float16 half8 __attribute__((ext_vector_type(8)));
typedef float    f32x4 __attribute__((ext_vector_type(4)));

// ---- workspace layout (bytes) ----
static const size_t OFF_QH = 0;
static const size_t OFF_F1 = (size_t)NB * NH1 * 4;
static const size_t OFF_F2 = OFF_F1 + (size_t)5 * 4 * 64 * 8 * 2;

__global__ void prep_weights(const float* __restrict__ W1, const float* __restrict__ W2,
                             _Float16* __restrict__ wF1, _Float16* __restrict__ wF2)
{
    const int tid = blockIdx.x * blockDim.x + threadIdx.x;
    const int stride = blockDim.x * gridDim.x;
    for (int i = tid; i < 5 * 4 * 64 * 8; i += stride) {
        const int j = i & 7, l = (i >> 3) & 63, s = (i >> 9) & 3, n = i >> 11;
        const int h  = n * 16 + (l & 15);
        const int kk = s * 32 + (l >> 4) * 8 + j;
        const float w = (kk < 64) ? (W1[(64 + kk) * NH1 + h] - W1[(128 + kk) * NH1 + h])
                                  :  W1[(128 + kk) * NH1 + h];
        wF1[i] = (_Float16)w;
    }
    for (int i = tid; i < 3 * 3 * 64 * 8; i += stride) {
        const int j = i & 7, l = (i >> 3) & 63;
        const int s = (i >> 9) % 3, n = i / 1536;
        const int kk = s * 32 + (l >> 4) * 8 + j;
        const int n2 = n * 16 + (l & 15);
        const float w = (kk < NH1 && n2 < NH2) ? W2[kk * NH2 + n2] : 0.f;
        wF2[i] = (_Float16)w;
    }
}

__global__ void prep_qh(const float* __restrict__ q, const float* __restrict__ W1,
                        const float* __restrict__ b1, float* __restrict__ wQh)
{
    const int idx = blockIdx.x * blockDim.x + threadIdx.x;
    if (idx >= NB * NH1) return;
    const int b = idx / NH1;
    const int h = idx - b * NH1;
    const float* qb = q + (size_t)b * DD;
    float acc = b1[h];
#pragma unroll 8
    for (int d = 0; d < DD; ++d)
        acc += qb[d] * (W1[d * NH1 + h] + W1[(128 + d) * NH1 + h]);
    wQh[idx] = acc;
}

// one wave per b; group-split online softmax; ALL loop-invariant scalars in LDS;
// ultra-lean arch-register body targeting the (256,3) cap -> 12 waves/CU
__global__ __launch_bounds__(256, 3)
void attn_main(const float* __restrict__ q, const float* __restrict__ k,
               const float* __restrict__ v, const int* __restrict__ mask,
               const float* __restrict__ Wf, const float* __restrict__ b2g,
               const float* __restrict__ bf,
               const float* __restrict__ wQh, const _Float16* __restrict__ wF1,
               const _Float16* __restrict__ wF2, float* __restrict__ out)
{
    __shared__ __align__(16) _Float16 sWF1[5 * 4 * 64 * 8];   // 20480 B
    __shared__ __align__(16) _Float16 sWF2[3 * 3 * 64 * 8];   //  9216 B
    __shared__ __align__(16) char sH1[4 * 3072];              // per-wave h1 (12288 B)
    __shared__ __align__(16) float sBias[4][208];             //  3328 B
    __shared__ __align__(16) _Float16 sQ16[4 * 64];           //   512 B
    __shared__ __align__(16) float sQh[4][80];                //  1280 B
    __shared__ float sWfv[48];                                //   192 B
    __shared__ float sB2v[48];                                //   192 B

    const int tid  = threadIdx.x;
    const int wid  = tid >> 6;
    const int lane = tid & 63;
    const int lr   = lane & 15;
    const int lg   = lane >> 4;
    const int b    = blockIdx.x * 4 + wid;      // each wave owns one batch row
    const int d0   = lr * 4;                    // this lane's v/out column slice
    const float bfv = bf[0];

    // stage weight fragments into LDS (block-shared)
    {
        f32x4* dst1 = (f32x4*)sWF1;
        const f32x4* src1 = (const f32x4*)wF1;
        for (int i = tid; i < 1280; i += 256) dst1[i] = src1[i];
        f32x4* dst2 = (f32x4*)sWF2;
        const f32x4* src2 = (const f32x4*)wF2;
        for (int i = tid; i < 576; i += 256) dst2[i] = src2[i];
    }

    // per-wave q (fp16) and qh slice into LDS  (FIX: strided loop covers 0..79)
    sQ16[wid * 64 + lane] = (_Float16)q[(size_t)b * DD + lane];
    for (int i = lane; i < NH1; i += 64)
        sQh[wid][i] = wQh[(size_t)b * NH1 + i];

    // block-shared Wf / b2 (zero-padded to 48) — first 96 threads handle both
    if (tid < 48)                    sWfv[tid] = (tid < NH2) ? Wf[tid] : 0.f;
    else if (tid >= 64 && tid < 112) { const int c = tid - 64; sB2v[c] = (c < NH2) ? b2g[c] : 0.f; }

    // per-wave mask bias: +big = keep, CONST_MIN = masked, -inf = pad rows (t>=200)
    for (int i = lane; i < 208; i += 64) {
        float bv;
        if (i < TT) bv = mask[(size_t)b * TT + i] ? 3.0e38f : -4294967295.0f;
        else        bv = -INFINITY;
        sBias[wid][i] = bv;
    }

    // zero-pad my wave's h1 cols 80..95 (slots 10,11), swizzled
    char* myH1 = sH1 + wid * 3072;
    if (lane < 32) {
        const int row = lane >> 1;
        const int slotL = 10 + (lane & 1);
        const f32x4 z4 = {};
        *(f32x4*)(myH1 + row * 192 + ((slotL ^ (row & 3)) << 4)) = z4;
    }

    __syncthreads();   // all LDS staging done

    const half8* sF1v = (const half8*)sWF1;
    const half8* sF2v = (const half8*)sWF2;
    const float* vb   = v + (size_t)b * (TT * DD);
    const float* kb   = k + (size_t)b * (TT * DD);
    const _Float16* myQ = sQ16 + wid * 64;
    const float* myQh = sQh[wid];

    // per-GROUP online softmax state
    float m = -INFINITY, s = 0.f;
    f32x4 acc = {};

    for (int mt = 0; mt < 13; ++mt) {
        // ---- k tile, convert immediately (no prefetch) ----
        const int t = min(mt * 16 + lr, TT - 1);
        const float* krow = kb + (size_t)t * DD;
        half8 af0, af1;
        {
            const f32x4 kc0 = *(const f32x4*)(krow + lg * 8);
            const f32x4 kc1 = *(const f32x4*)(krow + lg * 8 + 4);
            const f32x4 kc2 = *(const f32x4*)(krow + 32 + lg * 8);
            const f32x4 kc3 = *(const f32x4*)(krow + 32 + lg * 8 + 4);
#pragma unroll
            for (int j = 0; j < 4; ++j) {
                af0[j] = (_Float16)kc0[j];  af0[j + 4] = (_Float16)kc1[j];
                af1[j] = (_Float16)kc2[j];  af1[j + 4] = (_Float16)kc3[j];
            }
        }
        half8 af2, af3;
        {
            const half8 qf0 = *(const half8*)(myQ + lg * 8);
            const half8 qf1 = *(const half8*)(myQ + 32 + lg * 8);
            af2 = qf0 * af0;
            af3 = qf1 * af1;
        }

        // ---- layer 1 MFMA, qh (from LDS) folded into C-init, relu -> per-wave LDS ----
#pragma unroll
        for (int n = 0; n < 5; ++n) {
            const float qh = myQh[n * 16 + lr];
            f32x4 a = { qh, qh, qh, qh };
            a = __builtin_amdgcn_mfma_f32_16x16x32_f16(af0, sF1v[(n * 4 + 0) * 64 + lane], a, 0, 0, 0);
            a = __builtin_amdgcn_mfma_f32_16x16x32_f16(af1, sF1v[(n * 4 + 1) * 64 + lane], a, 0, 0, 0);
            a = __builtin_amdgcn_mfma_f32_16x16x32_f16(af2, sF1v[(n * 4 + 2) * 64 + lane], a, 0, 0, 0);
            a = __builtin_amdgcn_mfma_f32_16x16x32_f16(af3, sF1v[(n * 4 + 3) * 64 + lane], a, 0, 0, 0);
            const int slot   = (n * 16 + lr) >> 3;
            const int within = ((n * 16 + lr) & 7) * 2;
#pragma unroll
            for (int j = 0; j < 4; ++j) {
                const int r = lg * 4 + j;
                *(_Float16*)(myH1 + r * 192 + ((slot ^ (r & 3)) << 4) + within) = (_Float16)fmaxf(a[j], 0.f);
            }
        }

        // ---- issue v loads now (hidden under layer 2 + butterfly) ----
        const int tr = mt * 16 + lg * 4;
        const f32x4 vA = *(const f32x4*)(vb + (size_t)min(tr + 0, TT - 1) * DD + d0);
        const f32x4 vB = *(const f32x4*)(vb + (size_t)min(tr + 1, TT - 1) * DD + d0);
        const f32x4 vC = *(const f32x4*)(vb + (size_t)min(tr + 2, TT - 1) * DD + d0);
        const f32x4 vD = *(const f32x4*)(vb + (size_t)min(tr + 3, TT - 1) * DD + d0);

        // ---- layer 2 (wave-private rows), b2 (LDS) folded into C-init ----
        const half8 a2_0 = *(const half8*)(myH1 + lr * 192 + (((0 + lg) ^ (lr & 3)) << 4));
        const half8 a2_1 = *(const half8*)(myH1 + lr * 192 + (((4 + lg) ^ (lr & 3)) << 4));
        const half8 a2_2 = *(const half8*)(myH1 + lr * 192 + (((8 + lg) ^ (lr & 3)) << 4));

        float p0 = 0.f, p1 = 0.f, p2 = 0.f, p3 = 0.f;
#pragma unroll
        for (int n = 0; n < 3; ++n) {
            const float bb = sB2v[n * 16 + lr];
            const float wf = sWfv[n * 16 + lr];
            f32x4 c2 = { bb, bb, bb, bb };
            c2 = __builtin_amdgcn_mfma_f32_16x16x32_f16(a2_0, sF2v[(n * 3 + 0) * 64 + lane], c2, 0, 0, 0);
            c2 = __builtin_amdgcn_mfma_f32_16x16x32_f16(a2_1, sF2v[(n * 3 + 1) * 64 + lane], c2, 0, 0, 0);
            c2 = __builtin_amdgcn_mfma_f32_16x16x32_f16(a2_2, sF2v[(n * 3 + 2) * 64 + lane], c2, 0, 0, 0);
            p0 = fmaf(fmaxf(c2[0], 0.f), wf, p0);
            p1 = fmaf(fmaxf(c2[1], 0.f), wf, p1);
            p2 = fmaf(fmaxf(c2[2], 0.f), wf, p2);
            p3 = fmaf(fmaxf(c2[3], 0.f), wf, p3);
        }
        // butterfly over the 16-lane column group
#pragma unroll
        for (int off = 1; off < 16; off <<= 1) {
            p0 += __shfl_xor(p0, off);
            p1 += __shfl_xor(p1, off);
            p2 += __shfl_xor(p2, off);
            p3 += __shfl_xor(p3, off);
        }

        // ---- group-private online masked softmax + v accumulation ----
        const f32x4 bias4 = *(const f32x4*)&sBias[wid][mt * 16 + lg * 4];
        const float l0 = fminf(p0, bias4[0]) + bfv;
        const float l1 = fminf(p1, bias4[1]) + bfv;
        const float l2 = fminf(p2, bias4[2]) + bfv;
        const float l3 = fminf(p3, bias4[3]) + bfv;
        const float lmax = fmaxf(fmaxf(l0, l1), fmaxf(l2, l3));
        const float mnew = fmaxf(m, lmax);
        const float sc = __expf(m - mnew);
        const float w0 = __expf(l0 - mnew);
        const float w1 = __expf(l1 - mnew);
        const float w2 = __expf(l2 - mnew);
        const float w3 = __expf(l3 - mnew);
        s = s * sc + (w0 + w1 + w2 + w3);
        acc *= sc;
        acc += vA * w0;
        acc += vB * w1;
        acc += vC * w2;
        acc += vD * w3;
        m = mnew;
    }

    // ---- merge the 4 group states (lanes differ in bits 4,5) ----
    float mo = fmaxf(m, __shfl_xor(m, 16));
    mo = fmaxf(mo, __shfl_xor(mo, 32));
    const float f = __expf(m - mo);
    s *= f;
    acc *= f;
    s += __shfl_xor(s, 16);
    s += __shfl_xor(s, 32);
#pragma unroll
    for (int e = 0; e < 4; ++e) {
        float t = acc[e];
        t += __shfl_xor(t, 16);
        t += __shfl_xor(t, 32);
        acc[e] = t;
    }
    if (lg == 0) {
        const f32x4 res = acc / s;
        *(f32x4*)(out + (size_t)b * DD + d0) = res;
    }
}

extern "C" void kernel_launch(void* const* d_in, const int* in_sizes, int n_in,
                              void* d_out, int out_size, void* d_ws, size_t ws_size,
                              hipStream_t stream)
{
    const float* q   = (const float*)d_in[0];
    const float* k   = (const float*)d_in[1];
    const float* v   = (const float*)d_in[2];
    const int*  mask = (const int*)  d_in[3];
    const float* W1  = (const float*)d_in[4];
    const float* b1  = (const float*)d_in[5];
    const float* W2  = (const float*)d_in[6];
    const float* b2  = (const float*)d_in[7];
    const float* Wf  = (const float*)d_in[8];
    const float* bf  = (const float*)d_in[9];
    float* out = (float*)d_out;

    char* ws = (char*)d_ws;
    float*    wQh = (float*)   (ws + OFF_QH);
    _Float16* wF1 = (_Float16*)(ws + OFF_F1);
    _Float16* wF2 = (_Float16*)(ws + OFF_F2);

    prep_weights<<<16, 256, 0, stream>>>(W1, W2, wF1, wF2);
    prep_qh<<<(NB * NH1 + 255) / 256, 256, 0, stream>>>(q, W1, b1, wQh);
    attn_main<<<NB / 4, 256, 0, stream>>>(q, k, v, mask, Wf, b2, bf, wQh, wF1, wF2, out);
}

// Round 16
// 133.401 us; speedup vs baseline: 2.3217x; 2.3217x over previous
//
#include <hip/hip_runtime.h>
#include <cstddef>
#include <cmath>

#define NB  4096
#define TT  200
#define DD  64
#define NH1 80
#define NH2 40

typedef _Float16 half8 __attribute__((ext_vector_type(8)));
typedef float    f32x4 __attribute__((ext_vector_type(4)));

// ---- workspace layout (bytes) ----
static const size_t OFF_QH = 0;
static const size_t OFF_F1 = (size_t)NB * NH1 * 4;
static const size_t OFF_F2 = OFF_F1 + (size_t)5 * 4 * 64 * 8 * 2;

__global__ void prep_weights(const float* __restrict__ W1, const float* __restrict__ W2,
                             _Float16* __restrict__ wF1, _Float16* __restrict__ wF2)
{
    const int tid = blockIdx.x * blockDim.x + threadIdx.x;
    const int stride = blockDim.x * gridDim.x;
    for (int i = tid; i < 5 * 4 * 64 * 8; i += stride) {
        const int j = i & 7, l = (i >> 3) & 63, s = (i >> 9) & 3, n = i >> 11;
        const int h  = n * 16 + (l & 15);
        const int kk = s * 32 + (l >> 4) * 8 + j;
        const float w = (kk < 64) ? (W1[(64 + kk) * NH1 + h] - W1[(128 + kk) * NH1 + h])
                                  :  W1[(128 + kk) * NH1 + h];
        wF1[i] = (_Float16)w;
    }
    for (int i = tid; i < 3 * 3 * 64 * 8; i += stride) {
        const int j = i & 7, l = (i >> 3) & 63;
        const int s = (i >> 9) % 3, n = i / 1536;
        const int kk = s * 32 + (l >> 4) * 8 + j;
        const int n2 = n * 16 + (l & 15);
        const float w = (kk < NH1 && n2 < NH2) ? W2[kk * NH2 + n2] : 0.f;
        wF2[i] = (_Float16)w;
    }
}

__global__ void prep_qh(const float* __restrict__ q, const float* __restrict__ W1,
                        const float* __restrict__ b1, float* __restrict__ wQh)
{
    const int idx = blockIdx.x * blockDim.x + threadIdx.x;
    if (idx >= NB * NH1) return;
    const int b = idx / NH1;
    const int h = idx - b * NH1;
    const float* qb = q + (size_t)b * DD;
    float acc = b1[h];
#pragma unroll 8
    for (int d = 0; d < DD; ++d)
        acc += qb[d] * (W1[d * NH1 + h] + W1[(128 + d) * NH1 + h]);
    wQh[idx] = acc;
}

// one wave per b; group-split online softmax; loop-invariants in LDS;
// TWO independent tile-chains per iteration (lean ILP-2) at (256,2)
__global__ __launch_bounds__(256, 2)
void attn_main(const float* __restrict__ q, const float* __restrict__ k,
               const float* __restrict__ v, const int* __restrict__ mask,
               const float* __restrict__ Wf, const float* __restrict__ b2g,
               const float* __restrict__ bf,
               const float* __restrict__ wQh, const _Float16* __restrict__ wF1,
               const _Float16* __restrict__ wF2, float* __restrict__ out)
{
    __shared__ __align__(16) _Float16 sWF1[5 * 4 * 64 * 8];   // 20480 B
    __shared__ __align__(16) _Float16 sWF2[3 * 3 * 64 * 8];   //  9216 B
    __shared__ __align__(16) char sH1[4 * 2 * 3072];          // per-wave A/B h1 (24576 B)
    __shared__ __align__(16) float sBias[4][208];             //  3328 B
    __shared__ __align__(16) _Float16 sQ16[4 * 64];           //   512 B
    __shared__ __align__(16) float sQh[4][80];                //  1280 B
    __shared__ float sWfv[48];                                //   192 B
    __shared__ float sB2v[48];                                //   192 B

    const int tid  = threadIdx.x;
    const int wid  = tid >> 6;
    const int lane = tid & 63;
    const int lr   = lane & 15;
    const int lg   = lane >> 4;
    const int b    = blockIdx.x * 4 + wid;      // each wave owns one batch row
    const int d0   = lr * 4;                    // this lane's v/out column slice
    const float bfv = bf[0];

    // stage weight fragments into LDS (block-shared)
    {
        f32x4* dst1 = (f32x4*)sWF1;
        const f32x4* src1 = (const f32x4*)wF1;
        for (int i = tid; i < 1280; i += 256) dst1[i] = src1[i];
        f32x4* dst2 = (f32x4*)sWF2;
        const f32x4* src2 = (const f32x4*)wF2;
        for (int i = tid; i < 576; i += 256) dst2[i] = src2[i];
    }

    // per-wave q (fp16) and qh slice into LDS (strided loop covers 0..79)
    sQ16[wid * 64 + lane] = (_Float16)q[(size_t)b * DD + lane];
    for (int i = lane; i < NH1; i += 64)
        sQh[wid][i] = wQh[(size_t)b * NH1 + i];

    // block-shared Wf / b2 (zero-padded to 48)
    if (tid < 48)                     sWfv[tid] = (tid < NH2) ? Wf[tid] : 0.f;
    else if (tid >= 64 && tid < 112) { const int c = tid - 64; sB2v[c] = (c < NH2) ? b2g[c] : 0.f; }

    // per-wave mask bias: +big = keep, CONST_MIN = masked, -inf = pad rows (t>=200)
    for (int i = lane; i < 208; i += 64) {
        float bv;
        if (i < TT) bv = mask[(size_t)b * TT + i] ? 3.0e38f : -4294967295.0f;
        else        bv = -INFINITY;
        sBias[wid][i] = bv;
    }

    // per-wave A/B h1 buffers; zero-pad cols 80..95 (slots 10,11), swizzled
    char* h1A = sH1 + wid * 6144;
    char* h1B = h1A + 3072;
    if (lane < 32) {
        const int row = lane >> 1;
        const int slotL = 10 + (lane & 1);
        const f32x4 z4 = {};
        *(f32x4*)(h1A + row * 192 + ((slotL ^ (row & 3)) << 4)) = z4;
        *(f32x4*)(h1B + row * 192 + ((slotL ^ (row & 3)) << 4)) = z4;
    }

    __syncthreads();   // all LDS staging done

    const half8* sF1v = (const half8*)sWF1;
    const half8* sF2v = (const half8*)sWF2;
    const float* vb   = v + (size_t)b * (TT * DD);
    const float* kb   = k + (size_t)b * (TT * DD);
    const _Float16* myQ = sQ16 + wid * 64;
    const float* myQh = sQh[wid];

    // per-GROUP online softmax state
    float m = -INFINITY, s = 0.f;
    f32x4 acc = {};

    // ---- pairs: tiles 0..11 (all rows < 192 -> no clamps needed) ----
    for (int pair = 0; pair < 6; ++pair) {
        const int mtA = pair * 2, mtB = pair * 2 + 1;

        // q fragments for this pair (transient regs from LDS)
        const half8 qf0 = *(const half8*)(myQ + lg * 8);
        const half8 qf1 = *(const half8*)(myQ + 32 + lg * 8);

        // k tile A -> fragments
        half8 afA0, afA1, afA2, afA3;
        {
            const float* kr = kb + (size_t)(mtA * 16 + lr) * DD;
            const f32x4 c0 = *(const f32x4*)(kr + lg * 8);
            const f32x4 c1 = *(const f32x4*)(kr + lg * 8 + 4);
            const f32x4 c2 = *(const f32x4*)(kr + 32 + lg * 8);
            const f32x4 c3 = *(const f32x4*)(kr + 32 + lg * 8 + 4);
#pragma unroll
            for (int j = 0; j < 4; ++j) {
                afA0[j] = (_Float16)c0[j];  afA0[j + 4] = (_Float16)c1[j];
                afA1[j] = (_Float16)c2[j];  afA1[j + 4] = (_Float16)c3[j];
            }
            afA2 = qf0 * afA0;
            afA3 = qf1 * afA1;
        }
        // k tile B -> fragments
        half8 afB0, afB1, afB2, afB3;
        {
            const float* kr = kb + (size_t)(mtB * 16 + lr) * DD;
            const f32x4 c0 = *(const f32x4*)(kr + lg * 8);
            const f32x4 c1 = *(const f32x4*)(kr + lg * 8 + 4);
            const f32x4 c2 = *(const f32x4*)(kr + 32 + lg * 8);
            const f32x4 c3 = *(const f32x4*)(kr + 32 + lg * 8 + 4);
#pragma unroll
            for (int j = 0; j < 4; ++j) {
                afB0[j] = (_Float16)c0[j];  afB0[j + 4] = (_Float16)c1[j];
                afB1[j] = (_Float16)c2[j];  afB1[j + 4] = (_Float16)c3[j];
            }
            afB2 = qf0 * afB0;
            afB3 = qf1 * afB1;
        }

        // layer 1 for A and B (independent chains, interleaved by scheduler)
#pragma unroll
        for (int n = 0; n < 5; ++n) {
            const float qh = myQh[n * 16 + lr];
            f32x4 aA = { qh, qh, qh, qh };
            aA = __builtin_amdgcn_mfma_f32_16x16x32_f16(afA0, sF1v[(n * 4 + 0) * 64 + lane], aA, 0, 0, 0);
            aA = __builtin_amdgcn_mfma_f32_16x16x32_f16(afA1, sF1v[(n * 4 + 1) * 64 + lane], aA, 0, 0, 0);
            aA = __builtin_amdgcn_mfma_f32_16x16x32_f16(afA2, sF1v[(n * 4 + 2) * 64 + lane], aA, 0, 0, 0);
            aA = __builtin_amdgcn_mfma_f32_16x16x32_f16(afA3, sF1v[(n * 4 + 3) * 64 + lane], aA, 0, 0, 0);
            f32x4 aB = { qh, qh, qh, qh };
            aB = __builtin_amdgcn_mfma_f32_16x16x32_f16(afB0, sF1v[(n * 4 + 0) * 64 + lane], aB, 0, 0, 0);
            aB = __builtin_amdgcn_mfma_f32_16x16x32_f16(afB1, sF1v[(n * 4 + 1) * 64 + lane], aB, 0, 0, 0);
            aB = __builtin_amdgcn_mfma_f32_16x16x32_f16(afB2, sF1v[(n * 4 + 2) * 64 + lane], aB, 0, 0, 0);
            aB = __builtin_amdgcn_mfma_f32_16x16x32_f16(afB3, sF1v[(n * 4 + 3) * 64 + lane], aB, 0, 0, 0);
            const int slot   = (n * 16 + lr) >> 3;
            const int within = ((n * 16 + lr) & 7) * 2;
#pragma unroll
            for (int j = 0; j < 4; ++j) {
                const int r = lg * 4 + j;
                const int off = r * 192 + ((slot ^ (r & 3)) << 4) + within;
                *(_Float16*)(h1A + off) = (_Float16)fmaxf(aA[j], 0.f);
                *(_Float16*)(h1B + off) = (_Float16)fmaxf(aB[j], 0.f);
            }
        }

        // v loads for both tiles (issued now; consumed after butterfly)
        const int trA = mtA * 16 + lg * 4;
        const int trB = mtB * 16 + lg * 4;
        const f32x4 vA0 = *(const f32x4*)(vb + (size_t)(trA + 0) * DD + d0);
        const f32x4 vA1 = *(const f32x4*)(vb + (size_t)(trA + 1) * DD + d0);
        const f32x4 vA2 = *(const f32x4*)(vb + (size_t)(trA + 2) * DD + d0);
        const f32x4 vA3 = *(const f32x4*)(vb + (size_t)(trA + 3) * DD + d0);
        const f32x4 vB0 = *(const f32x4*)(vb + (size_t)(trB + 0) * DD + d0);
        const f32x4 vB1 = *(const f32x4*)(vb + (size_t)(trB + 1) * DD + d0);
        const f32x4 vB2 = *(const f32x4*)(vb + (size_t)(trB + 2) * DD + d0);
        const f32x4 vB3 = *(const f32x4*)(vb + (size_t)(trB + 3) * DD + d0);

        // layer 2 for A and B
        const half8 aA0 = *(const half8*)(h1A + lr * 192 + (((0 + lg) ^ (lr & 3)) << 4));
        const half8 aA1 = *(const half8*)(h1A + lr * 192 + (((4 + lg) ^ (lr & 3)) << 4));
        const half8 aA2 = *(const half8*)(h1A + lr * 192 + (((8 + lg) ^ (lr & 3)) << 4));
        const half8 aB0 = *(const half8*)(h1B + lr * 192 + (((0 + lg) ^ (lr & 3)) << 4));
        const half8 aB1 = *(const half8*)(h1B + lr * 192 + (((4 + lg) ^ (lr & 3)) << 4));
        const half8 aB2 = *(const half8*)(h1B + lr * 192 + (((8 + lg) ^ (lr & 3)) << 4));

        float pA0 = 0.f, pA1 = 0.f, pA2 = 0.f, pA3 = 0.f;
        float pB0 = 0.f, pB1 = 0.f, pB2 = 0.f, pB3 = 0.f;
#pragma unroll
        for (int n = 0; n < 3; ++n) {
            const float bb = sB2v[n * 16 + lr];
            const float wf = sWfv[n * 16 + lr];
            f32x4 cA = { bb, bb, bb, bb };
            cA = __builtin_amdgcn_mfma_f32_16x16x32_f16(aA0, sF2v[(n * 3 + 0) * 64 + lane], cA, 0, 0, 0);
            cA = __builtin_amdgcn_mfma_f32_16x16x32_f16(aA1, sF2v[(n * 3 + 1) * 64 + lane], cA, 0, 0, 0);
            cA = __builtin_amdgcn_mfma_f32_16x16x32_f16(aA2, sF2v[(n * 3 + 2) * 64 + lane], cA, 0, 0, 0);
            f32x4 cB = { bb, bb, bb, bb };
            cB = __builtin_amdgcn_mfma_f32_16x16x32_f16(aB0, sF2v[(n * 3 + 0) * 64 + lane], cB, 0, 0, 0);
            cB = __builtin_amdgcn_mfma_f32_16x16x32_f16(aB1, sF2v[(n * 3 + 1) * 64 + lane], cB, 0, 0, 0);
            cB = __builtin_amdgcn_mfma_f32_16x16x32_f16(aB2, sF2v[(n * 3 + 2) * 64 + lane], cB, 0, 0, 0);
            pA0 = fmaf(fmaxf(cA[0], 0.f), wf, pA0);
            pA1 = fmaf(fmaxf(cA[1], 0.f), wf, pA1);
            pA2 = fmaf(fmaxf(cA[2], 0.f), wf, pA2);
            pA3 = fmaf(fmaxf(cA[3], 0.f), wf, pA3);
            pB0 = fmaf(fmaxf(cB[0], 0.f), wf, pB0);
            pB1 = fmaf(fmaxf(cB[1], 0.f), wf, pB1);
            pB2 = fmaf(fmaxf(cB[2], 0.f), wf, pB2);
            pB3 = fmaf(fmaxf(cB[3], 0.f), wf, pB3);
        }

        // butterflies of both tiles interleaved (latency overlap)
#pragma unroll
        for (int off = 1; off < 16; off <<= 1) {
            pA0 += __shfl_xor(pA0, off);
            pB0 += __shfl_xor(pB0, off);
            pA1 += __shfl_xor(pA1, off);
            pB1 += __shfl_xor(pB1, off);
            pA2 += __shfl_xor(pA2, off);
            pB2 += __shfl_xor(pB2, off);
            pA3 += __shfl_xor(pA3, off);
            pB3 += __shfl_xor(pB3, off);
        }

        // online masked softmax + v accumulation: A then B
        {
            const f32x4 b4 = *(const f32x4*)&sBias[wid][mtA * 16 + lg * 4];
            const float l0 = fminf(pA0, b4[0]) + bfv;
            const float l1 = fminf(pA1, b4[1]) + bfv;
            const float l2 = fminf(pA2, b4[2]) + bfv;
            const float l3 = fminf(pA3, b4[3]) + bfv;
            const float lmax = fmaxf(fmaxf(l0, l1), fmaxf(l2, l3));
            const float mnew = fmaxf(m, lmax);
            const float sc = __expf(m - mnew);
            const float w0 = __expf(l0 - mnew);
            const float w1 = __expf(l1 - mnew);
            const float w2 = __expf(l2 - mnew);
            const float w3 = __expf(l3 - mnew);
            s = s * sc + (w0 + w1 + w2 + w3);
            acc *= sc;
            acc += vA0 * w0; acc += vA1 * w1; acc += vA2 * w2; acc += vA3 * w3;
            m = mnew;
        }
        {
            const f32x4 b4 = *(const f32x4*)&sBias[wid][mtB * 16 + lg * 4];
            const float l0 = fminf(pB0, b4[0]) + bfv;
            const float l1 = fminf(pB1, b4[1]) + bfv;
            const float l2 = fminf(pB2, b4[2]) + bfv;
            const float l3 = fminf(pB3, b4[3]) + bfv;
            const float lmax = fmaxf(fmaxf(l0, l1), fmaxf(l2, l3));
            const float mnew = fmaxf(m, lmax);
            const float sc = __expf(m - mnew);
            const float w0 = __expf(l0 - mnew);
            const float w1 = __expf(l1 - mnew);
            const float w2 = __expf(l2 - mnew);
            const float w3 = __expf(l3 - mnew);
            s = s * sc + (w0 + w1 + w2 + w3);
            acc *= sc;
            acc += vB0 * w0; acc += vB1 * w1; acc += vB2 * w2; acc += vB3 * w3;
            m = mnew;
        }
    }

    // ---- epilogue: tile 12 (rows 192..207, clamps; pad rows killed by -inf bias) ----
    {
        const int mt = 12;
        const int t = min(mt * 16 + lr, TT - 1);
        const float* kr = kb + (size_t)t * DD;
        half8 af0, af1;
        {
            const f32x4 c0 = *(const f32x4*)(kr + lg * 8);
            const f32x4 c1 = *(const f32x4*)(kr + lg * 8 + 4);
            const f32x4 c2 = *(const f32x4*)(kr + 32 + lg * 8);
            const f32x4 c3 = *(const f32x4*)(kr + 32 + lg * 8 + 4);
#pragma unroll
            for (int j = 0; j < 4; ++j) {
                af0[j] = (_Float16)c0[j];  af0[j + 4] = (_Float16)c1[j];
                af1[j] = (_Float16)c2[j];  af1[j + 4] = (_Float16)c3[j];
            }
        }
        const half8 qf0 = *(const half8*)(myQ + lg * 8);
        const half8 qf1 = *(const half8*)(myQ + 32 + lg * 8);
        const half8 af2 = qf0 * af0;
        const half8 af3 = qf1 * af1;

#pragma unroll
        for (int n = 0; n < 5; ++n) {
            const float qh = myQh[n * 16 + lr];
            f32x4 a = { qh, qh, qh, qh };
            a = __builtin_amdgcn_mfma_f32_16x16x32_f16(af0, sF1v[(n * 4 + 0) * 64 + lane], a, 0, 0, 0);
            a = __builtin_amdgcn_mfma_f32_16x16x32_f16(af1, sF1v[(n * 4 + 1) * 64 + lane], a, 0, 0, 0);
            a = __builtin_amdgcn_mfma_f32_16x16x32_f16(af2, sF1v[(n * 4 + 2) * 64 + lane], a, 0, 0, 0);
            a = __builtin_amdgcn_mfma_f32_16x16x32_f16(af3, sF1v[(n * 4 + 3) * 64 + lane], a, 0, 0, 0);
            const int slot   = (n * 16 + lr) >> 3;
            const int within = ((n * 16 + lr) & 7) * 2;
#pragma unroll
            for (int j = 0; j < 4; ++j) {
                const int r = lg * 4 + j;
                *(_Float16*)(h1A + r * 192 + ((slot ^ (r & 3)) << 4) + within) = (_Float16)fmaxf(a[j], 0.f);
            }
        }

        const int tr = mt * 16 + lg * 4;
        const f32x4 vA0 = *(const f32x4*)(vb + (size_t)min(tr + 0, TT - 1) * DD + d0);
        const f32x4 vA1 = *(const f32x4*)(vb + (size_t)min(tr + 1, TT - 1) * DD + d0);
        const f32x4 vA2 = *(const f32x4*)(vb + (size_t)min(tr + 2, TT - 1) * DD + d0);
        const f32x4 vA3 = *(const f32x4*)(vb + (size_t)min(tr + 3, TT - 1) * DD + d0);

        const half8 a0 = *(const half8*)(h1A + lr * 192 + (((0 + lg) ^ (lr & 3)) << 4));
        const half8 a1 = *(const half8*)(h1A + lr * 192 + (((4 + lg) ^ (lr & 3)) << 4));
        const half8 a2 = *(const half8*)(h1A + lr * 192 + (((8 + lg) ^ (lr & 3)) << 4));

        float p0 = 0.f, p1 = 0.f, p2 = 0.f, p3 = 0.f;
#pragma unroll
        for (int n = 0; n < 3; ++n) {
            const float bb = sB2v[n * 16 + lr];
            const float wf = sWfv[n * 16 + lr];
            f32x4 c2 = { bb, bb, bb, bb };
            c2 = __builtin_amdgcn_mfma_f32_16x16x32_f16(a0, sF2v[(n * 3 + 0) * 64 + lane], c2, 0, 0, 0);
            c2 = __builtin_amdgcn_mfma_f32_16x16x32_f16(a1, sF2v[(n * 3 + 1) * 64 + lane], c2, 0, 0, 0);
            c2 = __builtin_amdgcn_mfma_f32_16x16x32_f16(a2, sF2v[(n * 3 + 2) * 64 + lane], c2, 0, 0, 0);
            p0 = fmaf(fmaxf(c2[0], 0.f), wf, p0);
            p1 = fmaf(fmaxf(c2[1], 0.f), wf, p1);
            p2 = fmaf(fmaxf(c2[2], 0.f), wf, p2);
            p3 = fmaf(fmaxf(c2[3], 0.f), wf, p3);
        }
#pragma unroll
        for (int off = 1; off < 16; off <<= 1) {
            p0 += __shfl_xor(p0, off);
            p1 += __shfl_xor(p1, off);
            p2 += __shfl_xor(p2, off);
            p3 += __shfl_xor(p3, off);
        }

        const f32x4 b4 = *(const f32x4*)&sBias[wid][mt * 16 + lg * 4];
        const float l0 = fminf(p0, b4[0]) + bfv;
        const float l1 = fminf(p1, b4[1]) + bfv;
        const float l2 = fminf(p2, b4[2]) + bfv;
        const float l3 = fminf(p3, b4[3]) + bfv;
        const float lmax = fmaxf(fmaxf(l0, l1), fmaxf(l2, l3));
        const float mnew = fmaxf(m, lmax);
        const float sc = __expf(m - mnew);
        const float w0 = __expf(l0 - mnew);
        const float w1 = __expf(l1 - mnew);
        const float w2 = __expf(l2 - mnew);
        const float w3 = __expf(l3 - mnew);
        s = s * sc + (w0 + w1 + w2 + w3);
        acc *= sc;
        acc += vA0 * w0; acc += vA1 * w1; acc += vA2 * w2; acc += vA3 * w3;
        m = mnew;
    }

    // ---- merge the 4 group states (lanes differ in bits 4,5) ----
    float mo = fmaxf(m, __shfl_xor(m, 16));
    mo = fmaxf(mo, __shfl_xor(mo, 32));
    const float f = __expf(m - mo);
    s *= f;
    acc *= f;
    s += __shfl_xor(s, 16);
    s += __shfl_xor(s, 32);
#pragma unroll
    for (int e = 0; e < 4; ++e) {
        float t = acc[e];
        t += __shfl_xor(t, 16);
        t += __shfl_xor(t, 32);
        acc[e] = t;
    }
    if (lg == 0) {
        const f32x4 res = acc / s;
        *(f32x4*)(out + (size_t)b * DD + d0) = res;
    }
}

extern "C" void kernel_launch(void* const* d_in, const int* in_sizes, int n_in,
                              void* d_out, int out_size, void* d_ws, size_t ws_size,
                              hipStream_t stream)
{
    const float* q   = (const float*)d_in[0];
    const float* k   = (const float*)d_in[1];
    const float* v   = (const float*)d_in[2];
    const int*  mask = (const int*)  d_in[3];
    const float* W1  = (const float*)d_in[4];
    const float* b1  = (const float*)d_in[5];
    const float* W2  = (const float*)d_in[6];
    const float* b2  = (const float*)d_in[7];
    const float* Wf  = (const float*)d_in[8];
    const float* bf  = (const float*)d_in[9];
    float* out = (float*)d_out;

    char* ws = (char*)d_ws;
    float*    wQh = (float*)   (ws + OFF_QH);
    _Float16* wF1 = (_Float16*)(ws + OFF_F1);
    _Float16* wF2 = (_Float16*)(ws + OFF_F2);

    prep_weights<<<16, 256, 0, stream>>>(W1, W2, wF1, wF2);
    prep_qh<<<(NB * NH1 + 255) / 256, 256, 0, stream>>>(q, W1, b1, wQh);
    attn_main<<<NB / 4, 256, 0, stream>>>(q, k, v, mask, Wf, b2, bf, wQh, wF1, wF2, out);
}